// Round 11
// baseline (50.762 us; speedup 1.0000x reference)
//
#include <hip/hip_runtime.h>
#include <hip/hip_bf16.h>

#define THREADS 256
#define DIM 16

typedef __attribute__((ext_vector_type(8))) short bf16x8;
typedef __attribute__((ext_vector_type(16))) float f32x16;
typedef __attribute__((ext_vector_type(2))) float f32x2;

__device__ __forceinline__ float rawexp2(float a) { return __builtin_amdgcn_exp2f(a); }

// ---------------------------------------------------------------------------
// Prep: f32 -> bf16 RNE (truncation would bias each coordinate by -2^-9 and
// inject ~4.6e-6 bias into t1-t2). Outputs:
//   xbs/pbs = RNE(L2E * v~)             (A-operands, pre-scaled by log2 e)
//   pb      = v~                        (B-operand, particles only)
//   xn/pn   = -0.5*log2e*||v~||^2       (C-seed row terms, f32)
//   pfp     = exp2(-0.5*log2e*||p~||^2) (per-column factor, precomputed)
// Norms from the ROUNDED plain values; the t1 diagonal cancels to ~2^eta,
// eta ~ bf16 dot noise (random, ~1e-8 net on the output).
// ---------------------------------------------------------------------------
__global__ __launch_bounds__(THREADS) void prep_kernel(
    const float* __restrict__ x, int nx,
    const float* __restrict__ p, int np,
    short* __restrict__ xbs, float* __restrict__ xn,
    short* __restrict__ pbs, short* __restrict__ pb,
    float* __restrict__ pn, float* __restrict__ pfp)
{
    const float L2E  = 1.44269504088896340736f;
    const float HL2E = 0.72134752044448170368f;
    int i = blockIdx.x * THREADS + threadIdx.x;
    const float* src; short* ds; short* dp; float* dn; float* df;
    if (i < nx) {
        src = x + (size_t)i * DIM; ds = xbs + (size_t)i * DIM;
        dp = nullptr; dn = xn + i; df = nullptr;
    } else if (i < nx + np) {
        int j = i - nx;
        src = p + (size_t)j * DIM; ds = pbs + (size_t)j * DIM;
        dp = pb + (size_t)j * DIM; dn = pn + j; df = pfp + j;
    } else {
        return;
    }

    float nrm = 0.f;
    bf16x8 plo, phi, slo, shi;
#pragma unroll
    for (int k = 0; k < DIM; ++k) {
        unsigned u = __float_as_uint(src[k]);
        unsigned short r = (unsigned short)((u + 0x7FFFu + ((u >> 16) & 1u)) >> 16); // RNE
        float fr = __uint_as_float((unsigned)r << 16);
        nrm = fmaf(fr, fr, nrm);
        unsigned us = __float_as_uint(L2E * fr);
        unsigned short rs = (unsigned short)((us + 0x7FFFu + ((us >> 16) & 1u)) >> 16); // RNE
        if (k < 8) { plo[k] = (short)r; slo[k] = (short)rs; }
        else       { phi[k - 8] = (short)r; shi[k - 8] = (short)rs; }
    }
    *(bf16x8*)ds = slo; *((bf16x8*)ds + 1) = shi;
    if (dp) { *(bf16x8*)dp = plo; *((bf16x8*)dp + 1) = phi; }
    float ns = -HL2E * nrm;
    *dn = ns;
    if (df) *df = rawexp2(ns);
}

// ---------------------------------------------------------------------------
// Consume one MFMA result, phase-separated (R10-proven):
//   phase 1: 16 raw v_exp_f32 back-to-back (trans pipe streams)
//   phase 2: pairwise pk_add tree (7) + one pk_fma with pf
// ---------------------------------------------------------------------------
__device__ __forceinline__ void consume_tile(const f32x16& d, float f, f32x2& acc)
{
    f32x2 e0 = { rawexp2(d[0]),  rawexp2(d[1])  };
    f32x2 e1 = { rawexp2(d[2]),  rawexp2(d[3])  };
    f32x2 e2 = { rawexp2(d[4]),  rawexp2(d[5])  };
    f32x2 e3 = { rawexp2(d[6]),  rawexp2(d[7])  };
    f32x2 e4 = { rawexp2(d[8]),  rawexp2(d[9])  };
    f32x2 e5 = { rawexp2(d[10]), rawexp2(d[11]) };
    f32x2 e6 = { rawexp2(d[12]), rawexp2(d[13]) };
    f32x2 e7 = { rawexp2(d[14]), rawexp2(d[15]) };

    f32x2 s0 = e0 + e1;
    f32x2 s1 = e2 + e3;
    f32x2 s2 = e4 + e5;
    f32x2 s3 = e6 + e7;
    f32x2 u0 = s0 + s1;
    f32x2 u1 = s2 + s3;
    f32x2 t  = u0 + u1;
    f32x2 pf2 = {f, f};
    acc = t * pf2 + acc;
}

// ---------------------------------------------------------------------------
// A-PAIRED gram phase (R11): one wave owns a 64-row pair (a0 = rows
// row0..row0+31, a1 = rows row0+32..row0+63). Each column-tile's B-fragment
// and pf feed TWO MFMAs -> per-tile load/addr/loop glue halves.
// HARD CONSTRAINT (R8/R9 lesson): never more than 2 live f32x16 MFMA
// results — consume d0, reissue d0, consume d1, reissue d1.
// MFMA 32x32x16 bf16, A pre-scaled by L2E, C seeded with -HL2E*||row||^2:
//   d[r] = L2E*dot - HL2E*||row||^2 ; e = 2^d ; acc += pf_col * sum(e)
//   A/B frag: lane l holds point (l&31), k = (l>>5)*8 + i
//   D:        lane l, reg r -> row = (r&3) + 8*(r>>2) + 4*(l>>5), col = l&31
// d0 and d1 share col (l&31) and col-tile -> one pf per iteration.
// e = 2^d can reach ~2^72 on the t1 diagonal; no overflow, e*pf <= ~1.
// accA/accB: separate f32 chains per row-tile (combined later in f64).
// ntiles >= 2.
// ---------------------------------------------------------------------------
__device__ __forceinline__ void pair_phase(
    const short* __restrict__ rowsb, const float* __restrict__ rown,
    const short* __restrict__ colsb, const float* __restrict__ colpf,
    int row0, int ct0, int ntiles, int l31, int half,
    float& outA, float& outB)
{
    bf16x8 a0 = *(const bf16x8*)(rowsb + (size_t)(row0 + l31) * DIM + half * 8);
    bf16x8 a1 = *(const bf16x8*)(rowsb + (size_t)(row0 + 32 + l31) * DIM + half * 8);

    f32x16 c0, c1;
#pragma unroll
    for (int r = 0; r < 16; ++r) {
        int rrow = (r & 3) + 8 * (r >> 2) + 4 * half;
        c0[r] = rown[row0 + rrow];           // -HL2E*||row||^2 (prescaled)
        c1[r] = rown[row0 + 32 + rrow];
    }

    const short* bptr = colsb + ((size_t)ct0 * 32 + l31) * DIM + half * 8;
    const float* fptr = colpf + ct0 * 32 + l31;
    const size_t bstride = (size_t)32 * DIM;

    // prologue: tile 0 in flight, tile 1 operands loaded
    bf16x8 b0 = *(const bf16x8*)bptr;
    float  fC = fptr[0];
    f32x16 d0 = __builtin_amdgcn_mfma_f32_32x32x16_bf16(a0, b0, c0, 0, 0, 0);
    f32x16 d1 = __builtin_amdgcn_mfma_f32_32x32x16_bf16(a1, b0, c1, 0, 0, 0);
    bf16x8 bN = *(const bf16x8*)(bptr + bstride);
    float  fN = fptr[32];

    f32x2 accA = {0.f, 0.f}, accB = {0.f, 0.f};

    // iteration t: consume tile t, issue tile t+1, prefetch tile t+2
#pragma unroll 1
    for (int t = 0; t + 2 < ntiles; ++t) {
        bf16x8 bP = *(const bf16x8*)(bptr + (size_t)(t + 2) * bstride);
        float  fP = fptr[(t + 2) * 32];
        consume_tile(d0, fC, accA);
        d0 = __builtin_amdgcn_mfma_f32_32x32x16_bf16(a0, bN, c0, 0, 0, 0);
        consume_tile(d1, fC, accB);
        d1 = __builtin_amdgcn_mfma_f32_32x32x16_bf16(a1, bN, c1, 0, 0, 0);
        fC = fN; bN = bP; fN = fP;
    }
    // epilogue: consume tile ntiles-2, issue+consume tile ntiles-1
    consume_tile(d0, fC, accA);
    d0 = __builtin_amdgcn_mfma_f32_32x32x16_bf16(a0, bN, c0, 0, 0, 0);
    consume_tile(d1, fC, accB);
    d1 = __builtin_amdgcn_mfma_f32_32x32x16_bf16(a1, bN, c1, 0, 0, 0);
    consume_tile(d0, fN, accA);
    consume_tile(d1, fN, accB);

    outA = accA.x + accA.y;
    outB = accB.x + accB.y;
}

// ---------------------------------------------------------------------------
// Fused t1 + t2: 4096 waves (1024 blocks). Each wave: one 64-row pair x 8
// t1 col-tiles + one 64-row pair x 32 t2 col-tiles (= 16 + 64 tile-equiv,
// same totals as R10; perfect static balance).
//   t1: 128 row-pairs x 32 chunks of 8  -> 4096 assignments
//   t2: 512 row-pairs x 8  chunks of 32 -> 4096 assignments
// No min-waves launch_bounds clamp (R8/R9 lesson).
// ---------------------------------------------------------------------------
__global__ __launch_bounds__(THREADS) void gram_fused_kernel(
    const short* __restrict__ xbs, const float* __restrict__ xn,
    const short* __restrict__ pbs, const short* __restrict__ pb,
    const float* __restrict__ pn, const float* __restrict__ pfp,
    double sc1, double sc2,
    double* __restrict__ partials)
{
    const int lane = threadIdx.x & 63;
    const int wv   = threadIdx.x >> 6;
    const int l31  = lane & 31;
    const int half = lane >> 5;
    const int w    = blockIdx.x * (THREADS / 64) + wv;

    // t1: P x P  (rows = scaled particles, cols = plain particles)
    float a1s, b1s;
    {
        const int rp = w & 127;              // 128 row-pairs
        const int c0 = (w >> 7) * 8;         // 32 chunks x 8 tiles
        pair_phase(pbs, pn, pb, pfp, rp * 64, c0, 8, l31, half, a1s, b1s);
    }

    // t2: X x P
    float a2s, b2s;
    {
        const int rp = w & 511;              // 512 row-pairs
        const int c0 = (w >> 9) * 32;        // 8 chunks x 32 tiles
        pair_phase(xbs, xn, pb, pfp, rp * 64, c0, 32, l31, half, a2s, b2s);
    }

    double v = ((double)a1s + (double)b1s) * sc1
             - ((double)a2s + (double)b2s) * sc2;
#pragma unroll
    for (int off = 32; off > 0; off >>= 1) v += __shfl_down(v, off);

    __shared__ double sred[THREADS / 64];
    if (lane == 0) sred[wv] = v;
    __syncthreads();
    if (threadIdx.x == 0) {
        double tot = 0.0;
#pragma unroll
        for (int q = 0; q < THREADS / 64; ++q) tot += sred[q];
        partials[blockIdx.x] = tot;
    }
}

__global__ __launch_bounds__(THREADS) void finalize_kernel(
    const double* __restrict__ partials, int n, float* __restrict__ out)
{
    double v = 0.0;
    for (int i = threadIdx.x; i < n; i += THREADS) v += partials[i];
#pragma unroll
    for (int off = 32; off > 0; off >>= 1) v += __shfl_down(v, off);

    __shared__ double sred[THREADS / 64];
    const int lane = threadIdx.x & 63;
    const int wid = threadIdx.x >> 6;
    if (lane == 0) sred[wid] = v;
    __syncthreads();
    if (threadIdx.x == 0) {
        double tot = 0.0;
#pragma unroll
        for (int q = 0; q < THREADS / 64; ++q) tot += sred[q];
        out[0] = (float)tot;
    }
}

extern "C" void kernel_launch(void* const* d_in, const int* in_sizes, int n_in,
                              void* d_out, int out_size, void* d_ws, size_t ws_size,
                              hipStream_t stream) {
    const float* x = (const float*)d_in[0];         // [NX, 16]
    const float* particles = (const float*)d_in[1]; // [NP, 16]
    float* out = (float*)d_out;

    const int NX = in_sizes[0] / DIM;  // 32768
    const int NP = in_sizes[1] / DIM;  // 8192

    const int NBLOCKS = 1024;          // 4096 waves

    // ---- workspace layout (16B-aligned offsets) ----
    char* ws = (char*)d_ws;
    double* partials = (double*)ws;                  //    8 KB @ 0
    float*  xn  = (float*)(ws + 16384);              //  128 KB
    float*  pn  = (float*)(ws + 147456);             //   32 KB
    float*  pfp = (float*)(ws + 180224);             //   32 KB
    short*  xbs = (short*)(ws + 212992);             //    1 MB (scaled x)
    short*  pbs = (short*)(ws + 1261568);            //  256 KB (scaled p)
    short*  pb  = (short*)(ws + 1523712);            //  256 KB (plain p)

    // 1) convert + norms + column factors
    const int nprep = (NX + NP + THREADS - 1) / THREADS;
    prep_kernel<<<nprep, THREADS, 0, stream>>>(x, NX, particles, NP,
                                               xbs, xn, pbs, pb, pn, pfp);

    // 2) fused gram sums (scales applied per-wave in f64)
    gram_fused_kernel<<<NBLOCKS, THREADS, 0, stream>>>(
        xbs, xn, pbs, pb, pn, pfp,
        1.0 / ((double)NP * (double)NP),
        2.0 / ((double)NX * (double)NP),
        partials);

    // 3) combine
    finalize_kernel<<<1, THREADS, 0, stream>>>(partials, NBLOCKS, out);
}

// Round 12
// 47.187 us; speedup vs baseline: 1.0758x; 1.0758x over previous
//
#include <hip/hip_runtime.h>
#include <hip/hip_bf16.h>

#define THREADS 256
#define DIM 16

typedef __attribute__((ext_vector_type(8))) short bf16x8;
typedef __attribute__((ext_vector_type(16))) float f32x16;
typedef __attribute__((ext_vector_type(2))) float f32x2;

__device__ __forceinline__ float rawexp2(float a) { return __builtin_amdgcn_exp2f(a); }

// ---------------------------------------------------------------------------
// Prep: f32 -> bf16 RNE (truncation would bias each coordinate by -2^-9 and
// inject ~4.6e-6 bias into t1-t2). Outputs:
//   xbs/pbs = RNE(L2E * v~)             (A-operands, pre-scaled by log2 e)
//   pb      = v~                        (B-operand, particles only)
//   xn/pn   = -0.5*log2e*||v~||^2       (C-seed row terms, f32)
//   pfp     = exp2(-0.5*log2e*||p~||^2) (per-column factor, precomputed)
// Norms from the ROUNDED plain values; the t1 diagonal cancels to ~2^eta,
// eta ~ bf16 dot noise (random, ~1e-8 net on the output).
// ---------------------------------------------------------------------------
__global__ __launch_bounds__(THREADS) void prep_kernel(
    const float* __restrict__ x, int nx,
    const float* __restrict__ p, int np,
    short* __restrict__ xbs, float* __restrict__ xn,
    short* __restrict__ pbs, short* __restrict__ pb,
    float* __restrict__ pn, float* __restrict__ pfp)
{
    const float L2E  = 1.44269504088896340736f;
    const float HL2E = 0.72134752044448170368f;
    int i = blockIdx.x * THREADS + threadIdx.x;
    const float* src; short* ds; short* dp; float* dn; float* df;
    if (i < nx) {
        src = x + (size_t)i * DIM; ds = xbs + (size_t)i * DIM;
        dp = nullptr; dn = xn + i; df = nullptr;
    } else if (i < nx + np) {
        int j = i - nx;
        src = p + (size_t)j * DIM; ds = pbs + (size_t)j * DIM;
        dp = pb + (size_t)j * DIM; dn = pn + j; df = pfp + j;
    } else {
        return;
    }

    float nrm = 0.f;
    bf16x8 plo, phi, slo, shi;
#pragma unroll
    for (int k = 0; k < DIM; ++k) {
        unsigned u = __float_as_uint(src[k]);
        unsigned short r = (unsigned short)((u + 0x7FFFu + ((u >> 16) & 1u)) >> 16); // RNE
        float fr = __uint_as_float((unsigned)r << 16);
        nrm = fmaf(fr, fr, nrm);
        unsigned us = __float_as_uint(L2E * fr);
        unsigned short rs = (unsigned short)((us + 0x7FFFu + ((us >> 16) & 1u)) >> 16); // RNE
        if (k < 8) { plo[k] = (short)r; slo[k] = (short)rs; }
        else       { phi[k - 8] = (short)r; shi[k - 8] = (short)rs; }
    }
    *(bf16x8*)ds = slo; *((bf16x8*)ds + 1) = shi;
    if (dp) { *(bf16x8*)dp = plo; *((bf16x8*)dp + 1) = phi; }
    float ns = -HL2E * nrm;
    *dn = ns;
    if (df) *df = rawexp2(ns);
}

// ---------------------------------------------------------------------------
// Consume one MFMA result, phase-separated (R10-proven):
//   phase 1: 16 raw v_exp_f32 back-to-back (trans pipe streams)
//   phase 2: pairwise pk_add tree (7) + one pk_fma with pf
// ---------------------------------------------------------------------------
__device__ __forceinline__ void consume_tile(const f32x16& d, float f, f32x2& acc)
{
    f32x2 e0 = { rawexp2(d[0]),  rawexp2(d[1])  };
    f32x2 e1 = { rawexp2(d[2]),  rawexp2(d[3])  };
    f32x2 e2 = { rawexp2(d[4]),  rawexp2(d[5])  };
    f32x2 e3 = { rawexp2(d[6]),  rawexp2(d[7])  };
    f32x2 e4 = { rawexp2(d[8]),  rawexp2(d[9])  };
    f32x2 e5 = { rawexp2(d[10]), rawexp2(d[11]) };
    f32x2 e6 = { rawexp2(d[12]), rawexp2(d[13]) };
    f32x2 e7 = { rawexp2(d[14]), rawexp2(d[15]) };

    f32x2 s0 = e0 + e1;
    f32x2 s1 = e2 + e3;
    f32x2 s2 = e4 + e5;
    f32x2 s3 = e6 + e7;
    f32x2 u0 = s0 + s1;
    f32x2 u1 = s2 + s3;
    f32x2 t  = u0 + u1;
    f32x2 pf2 = {f, f};
    acc = t * pf2 + acc;
}

// ---------------------------------------------------------------------------
// R10's proven deep pipeline for the big t2 phase (ntiles even >= 2).
// d0/d1 ping-pong, <=2 live f32x16 MFMA results (R8/R9 lesson).
// MFMA 32x32x16 bf16, A pre-scaled by L2E, C seeded with -HL2E*||row||^2:
//   d[r] = L2E*dot - HL2E*||row||^2 ; e = 2^d ; acc += pf_col * sum(e)
//   A/B frag: lane l holds point (l&31), k = (l>>5)*8 + i
//   D:        lane l, reg r -> row = (r&3) + 8*(r>>2) + 4*(l>>5), col = l&31
// ---------------------------------------------------------------------------
__device__ __forceinline__ float gram_phase(
    const short* __restrict__ rowsb, const float* __restrict__ rown,
    const short* __restrict__ colsb, const float* __restrict__ colpf,
    int row0, int ct0, int ntiles, int l31, int half)
{
    bf16x8 afrag = *(const bf16x8*)(rowsb + (size_t)(row0 + l31) * DIM + half * 8);

    f32x16 cseed;
#pragma unroll
    for (int r = 0; r < 16; ++r) {
        int rrow = (r & 3) + 8 * (r >> 2) + 4 * half;
        cseed[r] = rown[row0 + rrow];      // = -HL2E*||row||^2 (prescaled)
    }

    const short* bptr = colsb + ((size_t)ct0 * 32 + l31) * DIM + half * 8;
    const float* fptr = colpf + ct0 * 32 + l31;
    const size_t bstride = (size_t)32 * DIM;

    bf16x8 b0 = *(const bf16x8*)bptr;
    bf16x8 b1 = *(const bf16x8*)(bptr + bstride);
    float  f0 = fptr[0];
    float  f1 = fptr[32];

    f32x16 d0 = __builtin_amdgcn_mfma_f32_32x32x16_bf16(afrag, b0, cseed, 0, 0, 0);
    f32x16 d1 = __builtin_amdgcn_mfma_f32_32x32x16_bf16(afrag, b1, cseed, 0, 0, 0);

    f32x2 acc = {0.f, 0.f};

#pragma unroll 1
    for (int t = 0; t + 2 < ntiles; t += 2) {
        bf16x8 bn0 = *(const bf16x8*)(bptr + (size_t)(t + 2) * bstride);
        float  fn0 = fptr[(t + 2) * 32];
        bf16x8 bn1 = *(const bf16x8*)(bptr + (size_t)(t + 3) * bstride);
        float  fn1 = fptr[(t + 3) * 32];

        consume_tile(d0, f0, acc);
        d0 = __builtin_amdgcn_mfma_f32_32x32x16_bf16(afrag, bn0, cseed, 0, 0, 0);
        consume_tile(d1, f1, acc);
        d1 = __builtin_amdgcn_mfma_f32_32x32x16_bf16(afrag, bn1, cseed, 0, 0, 0);

        f0 = fn0; f1 = fn1;
    }
    consume_tile(d0, f0, acc);
    consume_tile(d1, f1, acc);
    return acc.x + acc.y;
}

// ---------------------------------------------------------------------------
// t1 symmetric run: one row-tile rt, col-tiles [ct0, ct0+len), 1-deep
// pipeline (len can be 1..9 here; t1 is ~11% of work post-symmetry, so the
// shallower pipeline costs <0.3% total). If diagFirst, the first tile
// (ct0==rt) accumulates into accD (weight 1); all others into accU
// (weight 2, applied at combine).
// ---------------------------------------------------------------------------
__device__ __forceinline__ void tri_run(
    const short* __restrict__ rowsb, const float* __restrict__ rown,
    const short* __restrict__ colsb, const float* __restrict__ colpf,
    int rt, int ct0, int len, bool diagFirst, int l31, int half,
    f32x2& accD, f32x2& accU)
{
    if (len <= 0) return;
    const int row0 = rt * 32;
    bf16x8 afrag = *(const bf16x8*)(rowsb + (size_t)(row0 + l31) * DIM + half * 8);

    f32x16 cseed;
#pragma unroll
    for (int r = 0; r < 16; ++r) {
        int rrow = (r & 3) + 8 * (r >> 2) + 4 * half;
        cseed[r] = rown[row0 + rrow];
    }

    const short* bptr = colsb + ((size_t)ct0 * 32 + l31) * DIM + half * 8;
    const float* fptr = colpf + ct0 * 32 + l31;
    const size_t bstride = (size_t)32 * DIM;

    bf16x8 bC = *(const bf16x8*)bptr;
    float  fC = fptr[0];
    f32x16 d = __builtin_amdgcn_mfma_f32_32x32x16_bf16(afrag, bC, cseed, 0, 0, 0);

#pragma unroll 1
    for (int t = 0; t < len; ++t) {
        bf16x8 bN; float fN;
        if (t + 1 < len) {
            bN = *(const bf16x8*)(bptr + (size_t)(t + 1) * bstride);
            fN = fptr[(t + 1) * 32];
        }
        if (diagFirst && t == 0) {
            consume_tile(d, fC, accD);
        } else {
            consume_tile(d, fC, accU);
        }
        if (t + 1 < len) {
            d = __builtin_amdgcn_mfma_f32_32x32x16_bf16(afrag, bN, cseed, 0, 0, 0);
            fC = fN;
        }
    }
}

// ---------------------------------------------------------------------------
// Fused t1(symmetric) + t2: 4096 waves (1024 blocks, 4 blocks/CU).
// t1: upper-triangle tiles only (32896 of 65536; -10% total gram work).
//   128 jobs pair row-tiles (j, 255-j): segment A = (rt=j, ct=j..255),
//   length 256-j; segment B = (rt=255-j, ct=255-j..255), length j+1;
//   total exactly 257 tiles/job. 32 waves/job, contiguous ranges:
//   wave k=0 -> [0,9), k>=1 -> [8k+1, 8k+9). A wave's range may straddle
//   the segment boundary at m=256-j -> at most 2 tri_runs.
//   Diagonal tiles (i==0 and i==m) weight 1, others weight 2.
// t2: identical to R10 (1024 row-tiles x 4 chunks of 64 col-tiles).
// ---------------------------------------------------------------------------
__global__ __launch_bounds__(THREADS) void gram_fused_kernel(
    const short* __restrict__ xbs, const float* __restrict__ xn,
    const short* __restrict__ pbs, const short* __restrict__ pb,
    const float* __restrict__ pn, const float* __restrict__ pfp,
    double sc1, double sc2,
    double* __restrict__ partials)
{
    const int lane = threadIdx.x & 63;
    const int wv   = threadIdx.x >> 6;
    const int l31  = lane & 31;
    const int half = lane >> 5;
    const int w    = blockIdx.x * (THREADS / 64) + wv;

    // ---- t1: P x P upper triangle ----
    f32x2 accD = {0.f, 0.f}, accU = {0.f, 0.f};
    {
        const int j = w >> 5;                 // job 0..127
        const int k = w & 31;                 // wave-in-job
        const int s   = (k == 0) ? 0 : 8 * k + 1;
        const int cnt = (k == 0) ? 9 : 8;
        const int m = 256 - j;                // segment boundary

        // segment A piece: linear i in [s, min(s+cnt, m))
        {
            const int lo = s;
            const int hi = (s + cnt < m) ? (s + cnt) : m;
            const int lenA = hi - lo;
            if (lenA > 0)
                tri_run(pbs, pn, pb, pfp, j, j + lo, lenA, lo == 0,
                        l31, half, accD, accU);
        }
        // segment B piece: linear i in [max(s, m), s+cnt)
        {
            const int lo = (s > m) ? s : m;
            const int hi = s + cnt;
            const int lenB = hi - lo;
            if (lenB > 0) {
                const int i2 = lo - m;        // offset within segment B
                tri_run(pbs, pn, pb, pfp, 255 - j, (255 - j) + i2, lenB,
                        i2 == 0, l31, half, accD, accU);
            }
        }
    }
    float t1d = accD.x + accD.y;
    float t1u = accU.x + accU.y;

    // ---- t2: X x P (R10 structure, unchanged) ----
    const int rt2 = w & 1023;
    const int c20 = (w >> 10) * 64;
    float acc2 = gram_phase(xbs, xn, pb, pfp, rt2 * 32, c20, 64, l31, half);

    double v = ((double)t1d + 2.0 * (double)t1u) * sc1
             - (double)acc2 * sc2;
#pragma unroll
    for (int off = 32; off > 0; off >>= 1) v += __shfl_down(v, off);

    __shared__ double sred[THREADS / 64];
    if (lane == 0) sred[wv] = v;
    __syncthreads();
    if (threadIdx.x == 0) {
        double tot = 0.0;
#pragma unroll
        for (int q = 0; q < THREADS / 64; ++q) tot += sred[q];
        partials[blockIdx.x] = tot;
    }
}

__global__ __launch_bounds__(THREADS) void finalize_kernel(
    const double* __restrict__ partials, int n, float* __restrict__ out)
{
    double v = 0.0;
    for (int i = threadIdx.x; i < n; i += THREADS) v += partials[i];
#pragma unroll
    for (int off = 32; off > 0; off >>= 1) v += __shfl_down(v, off);

    __shared__ double sred[THREADS / 64];
    const int lane = threadIdx.x & 63;
    const int wid = threadIdx.x >> 6;
    if (lane == 0) sred[wid] = v;
    __syncthreads();
    if (threadIdx.x == 0) {
        double tot = 0.0;
#pragma unroll
        for (int q = 0; q < THREADS / 64; ++q) tot += sred[q];
        out[0] = (float)tot;
    }
}

extern "C" void kernel_launch(void* const* d_in, const int* in_sizes, int n_in,
                              void* d_out, int out_size, void* d_ws, size_t ws_size,
                              hipStream_t stream) {
    const float* x = (const float*)d_in[0];         // [NX, 16]
    const float* particles = (const float*)d_in[1]; // [NP, 16]
    float* out = (float*)d_out;

    const int NX = in_sizes[0] / DIM;  // 32768
    const int NP = in_sizes[1] / DIM;  // 8192

    const int NBLOCKS = 1024;          // 4096 waves

    // ---- workspace layout (16B-aligned offsets) ----
    char* ws = (char*)d_ws;
    double* partials = (double*)ws;                  //    8 KB @ 0
    float*  xn  = (float*)(ws + 16384);              //  128 KB
    float*  pn  = (float*)(ws + 147456);             //   32 KB
    float*  pfp = (float*)(ws + 180224);             //   32 KB
    short*  xbs = (short*)(ws + 212992);             //    1 MB (scaled x)
    short*  pbs = (short*)(ws + 1261568);            //  256 KB (scaled p)
    short*  pb  = (short*)(ws + 1523712);            //  256 KB (plain p)

    // 1) convert + norms + column factors
    const int nprep = (NX + NP + THREADS - 1) / THREADS;
    prep_kernel<<<nprep, THREADS, 0, stream>>>(x, NX, particles, NP,
                                               xbs, xn, pbs, pb, pn, pfp);

    // 2) fused gram sums (scales applied per-wave in f64)
    gram_fused_kernel<<<NBLOCKS, THREADS, 0, stream>>>(
        xbs, xn, pbs, pb, pn, pfp,
        1.0 / ((double)NP * (double)NP),
        2.0 / ((double)NX * (double)NP),
        partials);

    // 3) combine
    finalize_kernel<<<1, THREADS, 0, stream>>>(partials, NBLOCKS, out);
}